// Round 3
// baseline (423.356 us; speedup 1.0000x reference)
//
#include <hip/hip_runtime.h>
#include <math.h>

#define N 512
#define C 16
#define AGG_IN 1028   // N + (NLAYERS + N), NLAYERS=4
#define NBLK 256      // fused grid: 256 blocks x 512 threads, 2 q per block

typedef float v4f __attribute__((ext_vector_type(4)));

// Branchless tanh: tanh(x) = sign(x) * (1 - t)/(1 + t), t = exp(-2|x|).
__device__ __forceinline__ float fast_tanh(float x) {
    float ax = fabsf(x);
    float t  = __expf(-2.0f * ax);
    float r  = __fdividef(1.0f - t, 1.0f + t);
    return copysignf(r, x);
}

// Async global->LDS DMA, 16 B per active lane. Side-effecting intrinsic: the
// compiler cannot sink or discard it (unlike the register prefetch, which
// regalloc deleted — round 2 measured VGPR_Count=40, i.e. no pipeline).
// HW semantics: LDS dest = wave-uniform base + laneid*16; our masks are
// prefix-active and our layout lane-linear, so dest == g-order. [m97/m104]
__device__ __forceinline__ void async_copy16(const float* g, float* l) {
    __builtin_amdgcn_global_load_lds(
        (const __attribute__((address_space(1))) void*)g,
        (__attribute__((address_space(3))) void*)l,
        16, 0, 0);
}

// Copy nfloats (multiple of 4; all our streams are 16B-multiples) from g to
// LDS, 1 KB chunks round-robined over waves starting at virtual wave wv.
__device__ __forceinline__ void stage_stream(const float* __restrict__ g,
                                             float* l, int nfloats,
                                             int wv, int lane) {
    for (int off = wv * 256 + lane * 4; off < nfloats; off += 2048)
        async_copy16(g + off, l + off);
}

// Zero the grid-barrier counters each launch.
__global__ void bar_init_kernel(unsigned int* bar) {
    atomicExch(&bar[0], 0u);
    atomicExch(&bar[1], 0u);
    atomicExch(&bar[2], 0u);
    atomicExch(&bar[3], 0u);
}

// All 3 layer transitions fused; 24 "passes" (3 layers x 2 q x 4 p-chunks).
// Per pass, the full 45 KB working set is DMA'd into a double-buffered LDS:
// issue stage(P+1) -> compute(P from LDS) -> vmcnt(0)+barrier. ~45 KB/CU in
// flight converts the round-2 latency-bound serialization (684 GB/s, 8.5%
// peak) into a bandwidth-bound stream.
__global__ __launch_bounds__(512, 2) void dan_fused_kernel(
    const float* __restrict__ x,       // [N]
    float*       __restrict__ outp,    // [N] (reversed order)
    const float* __restrict__ vec_W,   // [LT,N,N,C]
    const float* __restrict__ vec_b,   // [LT,N,N,C]
    const float* __restrict__ syn_W1,  // [LT,N,N,3,C]
    const float* __restrict__ syn_b1,  // [LT,N,N,3]
    const float* __restrict__ syn_W2,  // [LT,N,N,3]
    const float* __restrict__ syn_b2,  // [LT,N,N]
    const float* __restrict__ agg_W1,  // [LT,N,3,AGG_IN]
    const float* __restrict__ agg_b1,  // [LT,N,3]
    const float* __restrict__ agg_W2,  // [LT,N,3]
    const float* __restrict__ agg_b2,  // [LT,N]
    float* a0, float* a1,              // workspace activations [N] each
    unsigned int* bar)                 // 2 barrier slots x {cnt, gen}
{
    const int bid  = blockIdx.x;
    const int t    = threadIdx.x;
    const int j    = t & 3;          // channel quad
    const int e    = t >> 2;         // edge slot 0..127 within pass
    const int wave = t >> 6;
    const int lane = t & 63;
    const int jc   = (j < 3) ? j : 2;

    // double-buffered pass working set: 2 x 11520 floats = 90 KB
    __shared__ __align__(16) float vwb[2][2048];   // vec_W chunk
    __shared__ __align__(16) float vbb[2][2048];   // vec_b chunk
    __shared__ __align__(16) float s1b[2][6144];   // syn_W1 chunk
    __shared__ __align__(16) float b1b[2][384];    // syn_b1
    __shared__ __align__(16) float w2b[2][384];    // syn_W2
    __shared__ __align__(16) float b2b[2][128];    // syn_b2
    __shared__ __align__(16) float awb[2][384];    // aW1 3 rows x 128 cols
    __shared__ float red[3][8];
    __shared__ float hsh[3];

    // Issue all DMAs for pass P into buffer bi. Any wave may carry any chunk.
    auto stage_pass = [&](int P, int bi) {
        const int   lP = P >> 3;
        const int   qP = bid * 2 + ((P >> 2) & 1);
        const int   p0 = (P & 3) * 128;
        const size_t edge0 = ((size_t)(lP * N + qP)) * N + p0;
        stage_stream(vec_W  + edge0 * 16, vwb[bi], 2048, wave, lane);
        stage_stream(vec_b  + edge0 * 16, vbb[bi], 2048, (wave + 4) & 7, lane);
        stage_stream(syn_W1 + edge0 * 48, s1b[bi], 6144, wave, lane);
        stage_stream(syn_b1 + edge0 * 3,  b1b[bi],  384, wave, lane);
        stage_stream(syn_W2 + edge0 * 3,  w2b[bi],  384, (wave + 6) & 7, lane);
        stage_stream(syn_b2 + edge0,      b2b[bi],  128, (wave + 4) & 7, lane);
        const float* awg = agg_W1 + ((size_t)(lP * N + qP)) * 3 * AGG_IN + p0;
        stage_stream(awg,              awb[bi] + 0,   128, (wave + 3) & 7, lane);
        stage_stream(awg + AGG_IN,     awb[bi] + 128, 128, (wave + 2) & 7, lane);
        stage_stream(awg + 2 * AGG_IN, awb[bi] + 256, 128, (wave + 1) & 7, lane);
    };

    float pv = 0.f;   // partial of dot(s[q,:], aW1[k=j,:N]) for j<3

    stage_pass(0, 0);

    #pragma unroll 1
    for (int P = 0; P < 24; ++P) {
        const int bi = P & 1;
        const int l  = P >> 3;
        const int q  = bid * 2 + ((P >> 2) & 1);
        const int p0 = (P & 3) * 128;

        // stage(P) complete (each wave waits its own DMAs, then all waves)
        asm volatile("s_waitcnt vmcnt(0)" ::: "memory");
        __syncthreads();

        // issue next pass's DMA before touching this pass's data
        if (P < 23) stage_pass(P + 1, bi ^ 1);

        const float* a_in = (l == 0) ? x : ((l == 1) ? a0 : a1);
        const float av = a_in[p0 + e];

        // e*16 + j*4 == t*4 for the lane-linear fat streams
        v4f w4  = *(const v4f*)&vwb[bi][t * 4];
        v4f b4  = *(const v4f*)&vbb[bi][t * 4];
        v4f sr0 = *(const v4f*)&s1b[bi][e * 48 +  0 + j * 4];
        v4f sr1 = *(const v4f*)&s1b[bi][e * 48 + 16 + j * 4];
        v4f sr2 = *(const v4f*)&s1b[bi][e * 48 + 32 + j * 4];

        float f0 = fast_tanh(fmaf(av, w4.x, b4.x));
        float f1 = fast_tanh(fmaf(av, w4.y, b4.y));
        float f2 = fast_tanh(fmaf(av, w4.z, b4.z));
        float f3 = fast_tanh(fmaf(av, w4.w, b4.w));

        float d0 = fmaf(sr0.x, f0, fmaf(sr0.y, f1, fmaf(sr0.z, f2, sr0.w * f3)));
        float d1 = fmaf(sr1.x, f0, fmaf(sr1.y, f1, fmaf(sr1.z, f2, sr1.w * f3)));
        float d2 = fmaf(sr2.x, f0, fmaf(sr2.y, f1, fmaf(sr2.z, f2, sr2.w * f3)));

        // combine the 4 channel-quads of this edge (quad = 4 adjacent lanes)
        d0 += __shfl_xor(d0, 1, 64);  d0 += __shfl_xor(d0, 2, 64);
        d1 += __shfl_xor(d1, 1, 64);  d1 += __shfl_xor(d1, 2, 64);
        d2 += __shfl_xor(d2, 1, 64);  d2 += __shfl_xor(d2, 2, 64);

        float h0 = fast_tanh(d0 + b1b[bi][e * 3 + 0]);
        float h1 = fast_tanh(d1 + b1b[bi][e * 3 + 1]);
        float h2 = fast_tanh(d2 + b1b[bi][e * 3 + 2]);
        float s = b2b[bi][e];
        s = fmaf(w2b[bi][e * 3 + 0], h0, s);
        s = fmaf(w2b[bi][e * 3 + 1], h1, s);
        s = fmaf(w2b[bi][e * 3 + 2], h2, s);
        s = fast_tanh(s);

        if (j < 3) pv = fmaf(s, awb[bi][jc * 128 + e], pv);

        // ---- per-q epilogue after its 4th pass ----
        if ((P & 3) == 3) {
            pv += __shfl_xor(pv, 4, 64);
            pv += __shfl_xor(pv, 8, 64);
            pv += __shfl_xor(pv, 16, 64);
            pv += __shfl_xor(pv, 32, 64);

            __syncthreads();                  // guard red/hsh reuse
            if (lane < 3) red[lane][wave] = pv;
            __syncthreads();

            if (t < 3) {
                const int k = t;
                float acc = 0.f;
                #pragma unroll
                for (int w8 = 0; w8 < 8; ++w8) acc += red[k][w8];
                const float* aW1 = agg_W1 + ((size_t)(l * N + q)) * 3 * AGG_IN
                                          + (size_t)k * AGG_IN;
                acc += aW1[N + (l + 1)];          // layer one-hot column
                acc += aW1[N + 4 + q];            // node one-hot column
                acc += agg_b1[((size_t)(l * N + q)) * 3 + k];
                hsh[k] = fast_tanh(acc);
            }
            __syncthreads();

            if (t == 0) {
                const float* aW2 = agg_W2 + ((size_t)(l * N + q)) * 3;
                float o = agg_b2[l * N + q];
                o = fmaf(aW2[0], hsh[0], o);
                o = fmaf(aW2[1], hsh[1], o);
                o = fmaf(aW2[2], hsh[2], o);
                if (l == 0)      a0[q] = o;
                else if (l == 1) a1[q] = o;
                else             outp[N - 1 - q] = o;   // reversed final output
            }
            pv = 0.f;
        }

        // ---- grid-wide barrier between layers (device-scope atomics) ----
        if ((P & 7) == 7 && l < 2) {
            __threadfence();              // make a-writes visible device-wide
            __syncthreads();              // whole block arrived
            if (t == 0) {
                unsigned int* cnt = bar + (size_t)l * 2;
                unsigned int* gen = bar + (size_t)l * 2 + 1;
                unsigned int g = atomicAdd(gen, 0u);      // observe current gen
                unsigned int v = atomicAdd(cnt, 1u);
                if (v == NBLK - 1) {
                    atomicExch(cnt, 0u);                  // self-reset for replay
                    atomicAdd(gen, 1u);                   // release
                } else {
                    int guard = 0;
                    while (atomicAdd(gen, 0u) == g) {
                        __builtin_amdgcn_s_sleep(8);
                        if (++guard > 4000000) break;     // safety valve
                    }
                }
            }
            __syncthreads();              // block waits for t==0; compiler fence
        }
    }
}

extern "C" void kernel_launch(void* const* d_in, const int* in_sizes, int n_in,
                              void* d_out, int out_size, void* d_ws, size_t ws_size,
                              hipStream_t stream) {
    const float* x      = (const float*)d_in[0];
    const float* vec_W  = (const float*)d_in[1];
    const float* vec_b  = (const float*)d_in[2];
    const float* syn_W1 = (const float*)d_in[3];
    const float* syn_b1 = (const float*)d_in[4];
    const float* syn_W2 = (const float*)d_in[5];
    const float* syn_b2 = (const float*)d_in[6];
    const float* agg_W1 = (const float*)d_in[7];
    const float* agg_b1 = (const float*)d_in[8];
    const float* agg_W2 = (const float*)d_in[9];
    const float* agg_b2 = (const float*)d_in[10];
    float* out = (float*)d_out;

    float* a0 = (float*)d_ws;                      // [N]
    float* a1 = a0 + N;                            // [N]
    unsigned int* bar = (unsigned int*)(a0 + 2 * N);  // 4 uints

    bar_init_kernel<<<1, 1, 0, stream>>>(bar);
    dan_fused_kernel<<<NBLK, 512, 0, stream>>>(
        x, out, vec_W, vec_b, syn_W1, syn_b1, syn_W2, syn_b2,
        agg_W1, agg_b1, agg_W2, agg_b2, a0, a1, bar);
}